// Round 5
// baseline (678.156 us; speedup 1.0000x reference)
//
#include <hip/hip_runtime.h>
#include <math.h>

// Problem constants: B=1024, T=256, D=128, H=64, 4H=256
constexpr int B_ = 1024;
constexpr int T_ = 256;
constexpr int D_ = 128;
constexpr int H_ = 64;

__device__ __forceinline__ float sigmoidf_(float x) {
    return 1.0f / (1.0f + __expf(-x));
}
// tanh(x) = 2*sigmoid(2x) - 1 ; overflow-safe at both ends
__device__ __forceinline__ float tanhf_(float x) {
    return fmaf(2.0f, 1.0f / (1.0f + __expf(-2.0f * x)), -1.0f);
}

// ---------------------------------------------------------------------------
// Fused LSTM, fp32, quad-slice layout. One block per batch element (1024
// blocks, 256 threads, 2 blocks/CU).
//   p = tid>>2  : hidden unit (0..63) this thread owns (all 4 gates of it)
//   s = tid&3   : k-slice (x dims s*32..+31, h dims s*16..+15)
// Per step: ONE barrier. Thread computes 4 gate partials (4x32 x-FMAs +
// 4x16 h-FMAs = 192), butterfly-reduces across the quad via __shfl_xor
// (width 4, in-wave, no barrier), then all quad lanes compute c/h
// redundantly (identical FP ops -> identical results). s==0 lane publishes
// h to the double-buffered LDS. x(t+1) row (512B) is staged by lanes 0..31
// of wave 0: load issued at the TOP of the step, ds_write at the BOTTOM,
// so the global latency hides behind the step's 192 FMAs.
// ---------------------------------------------------------------------------
__global__ __launch_bounds__(256, 2)
void lstm_quad_kernel(const float* __restrict__ x,     // [B,T,D]
                      const float* __restrict__ W_ih,  // [256,128]
                      const float* __restrict__ W_hh,  // [256,64]
                      const float* __restrict__ b_ih,  // [256]
                      const float* __restrict__ b_hh,  // [256]
                      const float* __restrict__ W1,    // [32,64]
                      const float* __restrict__ b1,    // [32]
                      const float* __restrict__ W2,    // [1,32]
                      const float* __restrict__ b2,    // [1]
                      float* __restrict__ out)         // [B]
{
    const int b   = blockIdx.x;
    const int tid = threadIdx.x;
    const int p   = tid >> 2;   // hidden unit
    const int s   = tid & 3;    // k-slice

    __shared__ __align__(16) float xs[2][D_];   // x row, double-buffered
    __shared__ __align__(16) float hs[2][H_];   // h,     double-buffered
    __shared__ __align__(16) float ys[32];      // head hidden

    // ---- preload weight slices into registers ----
    // gate rows: i=p, f=64+p, g=128+p, o=192+p
    float wih[4][32];   // [gate][k in s*32..s*32+31]
    float whh[4][16];   // [gate][k in s*16..s*16+15]
    #pragma unroll
    for (int gg = 0; gg < 4; ++gg) {
        const float* wr = W_ih + (size_t)(gg * 64 + p) * D_ + s * 32;
        #pragma unroll
        for (int k4 = 0; k4 < 8; ++k4) {
            float4 v = ((const float4*)wr)[k4];
            wih[gg][4*k4+0] = v.x; wih[gg][4*k4+1] = v.y;
            wih[gg][4*k4+2] = v.z; wih[gg][4*k4+3] = v.w;
        }
        const float* hr = W_hh + (size_t)(gg * 64 + p) * H_ + s * 16;
        #pragma unroll
        for (int k4 = 0; k4 < 4; ++k4) {
            float4 v = ((const float4*)hr)[k4];
            whh[gg][4*k4+0] = v.x; whh[gg][4*k4+1] = v.y;
            whh[gg][4*k4+2] = v.z; whh[gg][4*k4+3] = v.w;
        }
    }
    float bias[4];
    #pragma unroll
    for (int gg = 0; gg < 4; ++gg)
        bias[gg] = b_ih[gg * 64 + p] + b_hh[gg * 64 + p];

    const float* __restrict__ xrow = x + (size_t)b * T_ * D_;

    // ---- prologue: stage x(0), zero h(0) ----
    if (tid < 32) {
        float4 v = ((const float4*)xrow)[tid];
        *(float4*)&xs[0][tid * 4] = v;
    }
    if (tid < H_) hs[0][tid] = 0.0f;
    float c = 0.0f;
    float hval = 0.0f;
    __syncthreads();

    for (int t = 0; t < T_; ++t) {
        const int cur = t & 1;

        // ---- stage-load x(t+1) FIRST (consumed at end of step) ----
        float4 xnext;
        if (tid < 32) {
            const int tn = (t + 1 < T_) ? t + 1 : T_ - 1;
            xnext = ((const float4*)(xrow + (size_t)tn * D_))[tid];
        }

        // ---- gate partial dots over this thread's slice ----
        float a0 = 0.f, a1 = 0.f, a2 = 0.f, a3 = 0.f;
        const float4* xp4 = (const float4*)&xs[cur][s * 32];
        #pragma unroll
        for (int k4 = 0; k4 < 8; ++k4) {
            float4 v = xp4[k4];
            a0 = fmaf(wih[0][4*k4+0], v.x, a0); a0 = fmaf(wih[0][4*k4+1], v.y, a0);
            a0 = fmaf(wih[0][4*k4+2], v.z, a0); a0 = fmaf(wih[0][4*k4+3], v.w, a0);
            a1 = fmaf(wih[1][4*k4+0], v.x, a1); a1 = fmaf(wih[1][4*k4+1], v.y, a1);
            a1 = fmaf(wih[1][4*k4+2], v.z, a1); a1 = fmaf(wih[1][4*k4+3], v.w, a1);
            a2 = fmaf(wih[2][4*k4+0], v.x, a2); a2 = fmaf(wih[2][4*k4+1], v.y, a2);
            a2 = fmaf(wih[2][4*k4+2], v.z, a2); a2 = fmaf(wih[2][4*k4+3], v.w, a2);
            a3 = fmaf(wih[3][4*k4+0], v.x, a3); a3 = fmaf(wih[3][4*k4+1], v.y, a3);
            a3 = fmaf(wih[3][4*k4+2], v.z, a3); a3 = fmaf(wih[3][4*k4+3], v.w, a3);
        }
        const float4* hp4 = (const float4*)&hs[cur][s * 16];
        #pragma unroll
        for (int k4 = 0; k4 < 4; ++k4) {
            float4 v = hp4[k4];
            a0 = fmaf(whh[0][4*k4+0], v.x, a0); a0 = fmaf(whh[0][4*k4+1], v.y, a0);
            a0 = fmaf(whh[0][4*k4+2], v.z, a0); a0 = fmaf(whh[0][4*k4+3], v.w, a0);
            a1 = fmaf(whh[1][4*k4+0], v.x, a1); a1 = fmaf(whh[1][4*k4+1], v.y, a1);
            a1 = fmaf(whh[1][4*k4+2], v.z, a1); a1 = fmaf(whh[1][4*k4+3], v.w, a1);
            a2 = fmaf(whh[2][4*k4+0], v.x, a2); a2 = fmaf(whh[2][4*k4+1], v.y, a2);
            a2 = fmaf(whh[2][4*k4+2], v.z, a2); a2 = fmaf(whh[2][4*k4+3], v.w, a2);
            a3 = fmaf(whh[3][4*k4+0], v.x, a3); a3 = fmaf(whh[3][4*k4+1], v.y, a3);
            a3 = fmaf(whh[3][4*k4+2], v.z, a3); a3 = fmaf(whh[3][4*k4+3], v.w, a3);
        }

        // ---- butterfly reduce across the quad (in-wave, no barrier) ----
        a0 += __shfl_xor(a0, 1, 4);  a0 += __shfl_xor(a0, 2, 4);
        a1 += __shfl_xor(a1, 1, 4);  a1 += __shfl_xor(a1, 2, 4);
        a2 += __shfl_xor(a2, 1, 4);  a2 += __shfl_xor(a2, 2, 4);
        a3 += __shfl_xor(a3, 1, 4);  a3 += __shfl_xor(a3, 2, 4);

        // ---- elementwise (redundant in all 4 quad lanes, identical) ----
        float gi = sigmoidf_(bias[0] + a0);
        float gf = sigmoidf_(bias[1] + a1);
        float gg = tanhf_(bias[2] + a2);
        float go = sigmoidf_(bias[3] + a3);
        c    = fmaf(gf, c, gi * gg);
        hval = go * tanhf_(c);

        // ---- publish h(t+1); write x(t+1) staged at the top ----
        if (s == 0) hs[1 - cur][p] = hval;
        if (tid < 32) *(float4*)&xs[1 - cur][tid * 4] = xnext;

        __syncthreads();   // single barrier: publishes h(t+1) and x(t+1)
    }

    // ---- head: h(T) is in hs[0] (256 even) and in hval ----
    const float* hfin = hs[T_ & 1 ? 1 : 0];  // T_=256 -> hs[0]
    if (tid < 32) {
        float acc = b1[tid];
        const float4* w1r = (const float4*)(W1 + (size_t)tid * H_);
        #pragma unroll
        for (int k4 = 0; k4 < 16; ++k4) {
            float4 w4 = w1r[k4];
            float4 h4 = *(const float4*)&hfin[k4 * 4];
            acc = fmaf(w4.x, h4.x, acc); acc = fmaf(w4.y, h4.y, acc);
            acc = fmaf(w4.z, h4.z, acc); acc = fmaf(w4.w, h4.w, acc);
        }
        ys[tid] = fmaxf(acc, 0.0f);
    }
    __syncthreads();
    if (tid == 0) {
        float acc = b2[0];
        #pragma unroll
        for (int j = 0; j < 32; ++j) acc = fmaf(W2[j], ys[j], acc);
        out[b] = sigmoidf_(acc);
    }
}

extern "C" void kernel_launch(void* const* d_in, const int* in_sizes, int n_in,
                              void* d_out, int out_size, void* d_ws, size_t ws_size,
                              hipStream_t stream) {
    const float* x    = (const float*)d_in[0];
    const float* W_ih = (const float*)d_in[1];
    const float* W_hh = (const float*)d_in[2];
    const float* b_ih = (const float*)d_in[3];
    const float* b_hh = (const float*)d_in[4];
    const float* W1   = (const float*)d_in[5];
    const float* b1   = (const float*)d_in[6];
    const float* W2   = (const float*)d_in[7];
    const float* b2   = (const float*)d_in[8];
    float* out = (float*)d_out;

    lstm_quad_kernel<<<dim3(B_), dim3(256), 0, stream>>>(
        x, W_ih, W_hh, b_ih, b_hh, W1, b1, W2, b2, out);
}

// Round 6
// 453.169 us; speedup vs baseline: 1.4965x; 1.4965x over previous
//
#include <hip/hip_runtime.h>
#include <math.h>

// Problem constants: B=1024, T=256, D=128, H=64, 4H=256
constexpr int B_ = 1024;
constexpr int T_ = 256;
constexpr int D_ = 128;
constexpr int H_ = 64;

typedef short  v8s __attribute__((ext_vector_type(8)));   // 8 bf16 (4 VGPRs)
typedef float  v4f __attribute__((ext_vector_type(4)));   // MFMA acc

__device__ __forceinline__ float sigmoidf_(float x) {
    return 1.0f / (1.0f + __expf(-x));
}
// tanh(x) = 2*sigmoid(2x) - 1 ; overflow-safe at both ends
__device__ __forceinline__ float tanhf_(float x) {
    return fmaf(2.0f, 1.0f / (1.0f + __expf(-2.0f * x)), -1.0f);
}
__device__ __forceinline__ unsigned short f2bf(float f) {   // RNE f32->bf16
    unsigned u = __float_as_uint(f);
    u = (u + 0x7fffu + ((u >> 16) & 1u)) >> 16;
    return (unsigned short)u;
}
__device__ __forceinline__ v8s pack8(float4 a, float4 b) {
    v8s r;
    r[0] = (short)f2bf(a.x); r[1] = (short)f2bf(a.y);
    r[2] = (short)f2bf(a.z); r[3] = (short)f2bf(a.w);
    r[4] = (short)f2bf(b.x); r[5] = (short)f2bf(b.y);
    r[6] = (short)f2bf(b.z); r[7] = (short)f2bf(b.w);
    return r;
}

// ---------------------------------------------------------------------------
// Fully fused LSTM. 64 blocks x 256 threads; block bb owns batches bb*16..+15.
// Wave wv owns hidden cols [16wv,16wv+16): gate tiles gt = cls*4+wv, so
// (i,f,g,o) of hidden unit j = wv*16+q*4+r land in ONE lane's accumulators
// (MFMA C layout: col=lane&15=batch, row=q*4+r).
//
// Weights as wave-resident MFMA fragments (wih 16 v8s + whh 8 v8s + bias:
// ~112 VGPRs -- this pattern provably stays in registers, unlike scalar
// float arrays which the compiler rematerializes as per-step loads).
//
// Per step (ONE barrier):
//   - rec MFMA (2-chain) on h(t) from double-buffered LDS (slot = t&1)
//   - just-in-time projection MFMA (4-chain, K=128) for step t+1 from the
//     bf16 x-window in LDS -> xacc regs (no xp workspace, no layout shuffle)
//   - x staging for window w+1 (16 float4/thread/window spread over steps
//     0..4; loads issued at step top so the pre-barrier vmcnt(0) drain
//     overlaps the step's MFMA+transcendental work)
//   - elementwise (16 activations/lane) -> c,h ; packed-bf16 h write
// Global traffic: x read exactly once (134 MB). No stores until the head.
// ---------------------------------------------------------------------------
__global__ __launch_bounds__(256, 1)
void lstm_mono_kernel(const float* __restrict__ x,     // [B,T,D]
                      const float* __restrict__ W_ih,  // [256,128]
                      const float* __restrict__ W_hh,  // [256,64]
                      const float* __restrict__ b_ih,  // [256]
                      const float* __restrict__ b_hh,  // [256]
                      const float* __restrict__ W1,    // [32,64]
                      const float* __restrict__ b1,    // [32]
                      const float* __restrict__ W2,    // [1,32]
                      const float* __restrict__ b2,    // [1]
                      float* __restrict__ out)         // [B]
{
    const int bb   = blockIdx.x;
    const int tid  = threadIdx.x;
    const int wv   = tid >> 6;
    const int lane = tid & 63;
    const int q    = lane >> 4;
    const int ml   = lane & 15;

    // x window: [slot][tl][bt][d] bf16, row pad 128->136 (rows 272B, 16B-align)
    __shared__ __align__(16) unsigned short xbuf[2][8][16][136];  // 69.6 KB
    __shared__ __align__(16) unsigned short hbf[2][16][72];       // 4.6 KB
    __shared__ __align__(16) float hf[16][68];                    // 4.3 KB
    __shared__ __align__(16) float ys[16][36];                    // 2.3 KB

    // ---- wave-resident weight fragments ----
    v8s wih[4][4];   // [cls][ks] : A-frag of W_ih rows (m=gate), K=128
    v8s whh[4][2];   // [cls][ks] : A-frag of W_hh rows,          K=64
    v4f bias[4];     // [cls][r]
    #pragma unroll
    for (int cls = 0; cls < 4; ++cls) {
        const int gr = (cls * 4 + wv) * 16 + ml;     // A m-index = ml
        #pragma unroll
        for (int ks = 0; ks < 4; ++ks) {
            const float* p = W_ih + (size_t)gr * D_ + ks * 32 + q * 8;
            wih[cls][ks] = pack8(((const float4*)p)[0], ((const float4*)p)[1]);
        }
        #pragma unroll
        for (int ks = 0; ks < 2; ++ks) {
            const float* p = W_hh + (size_t)gr * H_ + ks * 32 + q * 8;
            whh[cls][ks] = pack8(((const float4*)p)[0], ((const float4*)p)[1]);
        }
        #pragma unroll
        for (int r = 0; r < 4; ++r) {
            const int g2 = (cls * 4 + wv) * 16 + q * 4 + r;   // C row = q*4+r
            bias[cls][r] = b_ih[g2] + b_hh[g2];
        }
    }

    // zero both h slots (2*16*72 shorts = 1152 dwords)
    for (int i = tid; i < 1152; i += 256) ((unsigned*)hbf)[i] = 0u;

    const float* __restrict__ xb = x + (size_t)(bb * 16) * T_ * D_;
    const int stl = tid >> 5;      // staging: local t (0..7)
    const int sc4 = tid & 31;      // staging: float4 index in the 128-d row

    // ---- prologue: stage window 0 (t = 0..7) into xbuf[0] ----
    #pragma unroll
    for (int bt = 0; bt < 16; ++bt) {
        float4 v = ((const float4*)(xb + ((size_t)bt * T_ + stl) * D_))[sc4];
        short4 s;
        s.x = (short)f2bf(v.x); s.y = (short)f2bf(v.y);
        s.z = (short)f2bf(v.z); s.w = (short)f2bf(v.w);
        *(short4*)&xbuf[0][stl][bt][sc4 * 4] = s;
    }
    __syncthreads();

    float cst[4]   = {0.f, 0.f, 0.f, 0.f};
    float hlast[4] = {0.f, 0.f, 0.f, 0.f};

    // ---- initial projection for t = 0 ----
    v4f xacc[4];
    #pragma unroll
    for (int cls = 0; cls < 4; ++cls) xacc[cls] = bias[cls];
    #pragma unroll
    for (int ks = 0; ks < 4; ++ks) {
        v8s bf = *(const v8s*)&xbuf[0][0][ml][ks * 32 + q * 8];
        #pragma unroll
        for (int cls = 0; cls < 4; ++cls)
            xacc[cls] = __builtin_amdgcn_mfma_f32_16x16x32_bf16(
                wih[cls][ks], bf, xacc[cls], 0, 0, 0);
    }

    // ---- main loop: 32 windows x 8 steps (fully unrolled inner) ----
    for (int w32 = 0; w32 < 32; ++w32) {
        const int  wp    = w32 & 1;
        const bool stage = (w32 < 31);
        float4 sA[4], sB[4];    // staging chunks, statically indexed

        #pragma unroll
        for (int tl = 0; tl < 8; ++tl) {
            // -- staging loads (issued first: hidden behind this step's work)
            if (stage) {
                if (tl == 0) {
                    #pragma unroll
                    for (int j = 0; j < 4; ++j)
                        sA[j] = ((const float4*)(xb + ((size_t)(j) * T_
                                 + (w32 + 1) * 8 + stl) * D_))[sc4];
                } else if (tl == 1) {
                    #pragma unroll
                    for (int j = 0; j < 4; ++j)
                        sB[j] = ((const float4*)(xb + ((size_t)(4 + j) * T_
                                 + (w32 + 1) * 8 + stl) * D_))[sc4];
                } else if (tl == 2) {
                    #pragma unroll
                    for (int j = 0; j < 4; ++j)
                        sA[j] = ((const float4*)(xb + ((size_t)(8 + j) * T_
                                 + (w32 + 1) * 8 + stl) * D_))[sc4];
                } else if (tl == 3) {
                    #pragma unroll
                    for (int j = 0; j < 4; ++j)
                        sB[j] = ((const float4*)(xb + ((size_t)(12 + j) * T_
                                 + (w32 + 1) * 8 + stl) * D_))[sc4];
                }
            }

            // -- recurrent MFMA on h(t): slot = tl&1 (w32*8 even)
            v8s h0 = *(const v8s*)&hbf[tl & 1][ml][q * 8];
            v8s h1 = *(const v8s*)&hbf[tl & 1][ml][32 + q * 8];
            v4f acc[4];
            #pragma unroll
            for (int cls = 0; cls < 4; ++cls) {
                acc[cls] = __builtin_amdgcn_mfma_f32_16x16x32_bf16(
                    whh[cls][0], h0, xacc[cls], 0, 0, 0);
                acc[cls] = __builtin_amdgcn_mfma_f32_16x16x32_bf16(
                    whh[cls][1], h1, acc[cls], 0, 0, 0);
            }

            // -- just-in-time projection for t+1 (independent of h)
            {
                const int nslot = (tl == 7) ? 1 - wp : wp;
                const int tln   = (tl + 1) & 7;
                v4f xn[4];
                #pragma unroll
                for (int cls = 0; cls < 4; ++cls) xn[cls] = bias[cls];
                #pragma unroll
                for (int ks = 0; ks < 4; ++ks) {
                    v8s bf = *(const v8s*)&xbuf[nslot][tln][ml][ks * 32 + q * 8];
                    #pragma unroll
                    for (int cls = 0; cls < 4; ++cls)
                        xn[cls] = __builtin_amdgcn_mfma_f32_16x16x32_bf16(
                            wih[cls][ks], bf, xn[cls], 0, 0, 0);
                }
                #pragma unroll
                for (int cls = 0; cls < 4; ++cls) xacc[cls] = xn[cls];
            }

            // -- staging writes (chunk loaded last step; WAR-safe vs barrier)
            if (stage) {
                if (tl == 1 || tl == 3) {
                    const int c0 = (tl == 1) ? 0 : 8;
                    #pragma unroll
                    for (int j = 0; j < 4; ++j) {
                        float4 v = sA[j];
                        short4 s;
                        s.x = (short)f2bf(v.x); s.y = (short)f2bf(v.y);
                        s.z = (short)f2bf(v.z); s.w = (short)f2bf(v.w);
                        *(short4*)&xbuf[1 - wp][stl][c0 + j][sc4 * 4] = s;
                    }
                } else if (tl == 2 || tl == 4) {
                    const int c0 = (tl == 2) ? 4 : 12;
                    #pragma unroll
                    for (int j = 0; j < 4; ++j) {
                        float4 v = sB[j];
                        short4 s;
                        s.x = (short)f2bf(v.x); s.y = (short)f2bf(v.y);
                        s.z = (short)f2bf(v.z); s.w = (short)f2bf(v.w);
                        *(short4*)&xbuf[1 - wp][stl][c0 + j][sc4 * 4] = s;
                    }
                }
            }

            // -- elementwise: (b = bb*16+ml, j = wv*16+q*4+r)
            #pragma unroll
            for (int r = 0; r < 4; ++r) {
                float gi = sigmoidf_(acc[0][r]);
                float gf = sigmoidf_(acc[1][r]);
                float gg = tanhf_(acc[2][r]);
                float go = sigmoidf_(acc[3][r]);
                cst[r]   = fmaf(gf, cst[r], gi * gg);
                hlast[r] = go * tanhf_(cst[r]);
            }

            // -- publish h(t+1) to the other slot
            {
                ushort4 hp;
                hp.x = f2bf(hlast[0]); hp.y = f2bf(hlast[1]);
                hp.z = f2bf(hlast[2]); hp.w = f2bf(hlast[3]);
                *(ushort4*)&hbf[1 - (tl & 1)][ml][wv * 16 + q * 4] = hp;
            }

            __syncthreads();   // single barrier per step
        }
    }

    // ---- head: h(T) lives in hlast (f32) ----
    {
        float4 hv;
        hv.x = hlast[0]; hv.y = hlast[1]; hv.z = hlast[2]; hv.w = hlast[3];
        *(float4*)&hf[ml][wv * 16 + q * 4] = hv;
    }
    __syncthreads();
    {
        const int bloc = tid & 15, jj = tid >> 4;
        #pragma unroll
        for (int j2 = 0; j2 < 2; ++j2) {
            const int j = jj + j2 * 16;
            float acc = b1[j];
            const float4* w1r = (const float4*)(W1 + (size_t)j * H_);
            #pragma unroll
            for (int k4 = 0; k4 < 16; ++k4) {
                float4 h4 = *(const float4*)&hf[bloc][k4 * 4];
                float4 w4 = w1r[k4];
                acc = fmaf(w4.x, h4.x, acc); acc = fmaf(w4.y, h4.y, acc);
                acc = fmaf(w4.z, h4.z, acc); acc = fmaf(w4.w, h4.w, acc);
            }
            ys[bloc][j] = fmaxf(acc, 0.0f);
        }
    }
    __syncthreads();
    if (tid < 16) {
        float a = b2[0];
        #pragma unroll
        for (int j = 0; j < 32; ++j) a = fmaf(W2[j], ys[tid][j], a);
        out[bb * 16 + tid] = sigmoidf_(a);
    }
}

extern "C" void kernel_launch(void* const* d_in, const int* in_sizes, int n_in,
                              void* d_out, int out_size, void* d_ws, size_t ws_size,
                              hipStream_t stream) {
    const float* x    = (const float*)d_in[0];
    const float* W_ih = (const float*)d_in[1];
    const float* W_hh = (const float*)d_in[2];
    const float* b_ih = (const float*)d_in[3];
    const float* b_hh = (const float*)d_in[4];
    const float* W1   = (const float*)d_in[5];
    const float* b1   = (const float*)d_in[6];
    const float* W2   = (const float*)d_in[7];
    const float* b2   = (const float*)d_in[8];
    float* out = (float*)d_out;

    lstm_mono_kernel<<<dim3(B_ / 16), dim3(256), 0, stream>>>(
        x, W_ih, W_hh, b_ih, b_hh, W1, b1, W2, b2, out);
}